// Round 6
// baseline (717.553 us; speedup 1.0000x reference)
//
#include <hip/hip_runtime.h>

#define B_ 2
#define S_ 2048
#define E_ 2048
#define H_ 16
#define G_ 4
#define HD_ 128
#define GD_ 512
#define KVLD_ 1024
#define QKVN_ 3072
#define M_ (B_*S_)   // 4096

using u16 = unsigned short;
using u32 = unsigned int;
typedef __attribute__((ext_vector_type(8))) short short8;
typedef __attribute__((ext_vector_type(4))) float f32x4;

// scale * log2(e), folded into Q so scores come out in log2 domain
#define QSCL 0.12751891114f   // (1/sqrt(128)) * 1.4426950408889634
#define MASKED_L2 (-14427.0f) // -10000 * log2(e)

__device__ __forceinline__ u16 f2bf(float f) {
  union { float f; unsigned u; } v; v.f = f;
  unsigned r = v.u + 0x7fff + ((v.u >> 16) & 1);  // RNE
  return (u16)(r >> 16);
}

__device__ __forceinline__ void async16(const void* g, void* l) {
  __builtin_amdgcn_global_load_lds((const __attribute__((address_space(1))) unsigned int*)g,
                                   (__attribute__((address_space(3))) unsigned int*)l, 16, 0, 0);
}

// ---------------- elementwise f32 -> bf16 cast (x) ----------------
__global__ __launch_bounds__(256) void cast_f32_bf16(const float* __restrict__ in,
                                                     u16* __restrict__ out, int n4) {
  int i = blockIdx.x * 256 + threadIdx.x;
  if (i >= n4) return;
  float4 v = ((const float4*)in)[i];
  union { u16 o[4]; uint2 u; } pk;
  pk.o[0] = f2bf(v.x); pk.o[1] = f2bf(v.y); pk.o[2] = f2bf(v.z); pk.o[3] = f2bf(v.w);
  *(uint2*)(out + (size_t)i * 4) = pk.u;
}

__global__ __launch_bounds__(256) void concat_bias3(const float* __restrict__ a,
                                                    const float* __restrict__ b,
                                                    const float* __restrict__ c,
                                                    float* __restrict__ o) {
  int t = blockIdx.x * 256 + threadIdx.x;
  if (t < 2048) o[t] = a[t];
  else if (t < 2560) o[t] = b[t - 2048];
  else if (t < 3072) o[t] = c[t - 2560];
}

// ------------- W (KxN f32) -> Wt (NxK bf16) transpose-cast -------------
__global__ __launch_bounds__(256) void transpose_cast(const float* __restrict__ W,
                                                      u16* __restrict__ Wt, int K, int N) {
  __shared__ u16 tile[64 * 72];
  int n0 = blockIdx.x * 64, k0 = blockIdx.y * 64;
  int t = threadIdx.x;
  int row = t >> 2;       // k_local 0..63
  int seg = t & 3;        // 16 f32 each
  const float* src = W + (size_t)(k0 + row) * N + n0 + seg * 16;
  #pragma unroll
  for (int i = 0; i < 4; ++i) {
    float4 v = *(const float4*)(src + i * 4);
    int nl = seg * 16 + i * 4;
    tile[(nl + 0) * 72 + row] = f2bf(v.x);
    tile[(nl + 1) * 72 + row] = f2bf(v.y);
    tile[(nl + 2) * 72 + row] = f2bf(v.z);
    tile[(nl + 3) * 72 + row] = f2bf(v.w);
  }
  __syncthreads();
  int nl = t >> 2, s2 = t & 3;   // 16 bf16 per thread
  u16* dst = Wt + (size_t)(n0 + nl) * K + k0 + s2 * 16;
  *(uint4*)dst       = *(const uint4*)&tile[nl * 72 + s2 * 16];
  *(uint4*)(dst + 8) = *(const uint4*)&tile[nl * 72 + s2 * 16 + 8];
}

// ------------- V (from KVb, cols 512..1023) -> Vtg[(bb*G+g)*HD+n][S] with
// kv permuted within each 64-block: phys = (kv&15)*4 + (kv>>4)   (matches P
// A-frag slot order: phys p holds kv = (p&3)*16 + (p>>2)) -------------
__global__ __launch_bounds__(256) void transpose_v(const u16* __restrict__ KVb, u16* __restrict__ Vtg) {
  __shared__ u16 tile[64 * 72];
  int kv0 = blockIdx.x * 64;      // over M_
  int gn0 = blockIdx.y * 64;      // over GD_
  int t = threadIdx.x;
  int row = t >> 2, seg = t & 3;
  int prow = (row & 15) * 4 + (row >> 4);   // kv permutation
  const u16* src = KVb + (size_t)(kv0 + row) * KVLD_ + 512 + gn0 + seg * 16;
  union { uint4 v; u16 s[8]; } a, b;
  a.v = *(const uint4*)src; b.v = *(const uint4*)(src + 8);
  #pragma unroll
  for (int j = 0; j < 8; ++j) tile[(seg * 16 + j) * 72 + prow] = a.s[j];
  #pragma unroll
  for (int j = 0; j < 8; ++j) tile[(seg * 16 + 8 + j) * 72 + prow] = b.s[j];
  __syncthreads();
  int gl = t >> 2, ks2 = t & 3;
  int bb = kv0 >> 11;
  int s0 = kv0 & 2047;
  int gn = gn0 + gl;
  u16* dst = Vtg + (size_t)(bb * 512 + gn) * S_ + s0 + ks2 * 16;
  *(uint4*)dst       = *(const uint4*)&tile[gl * 72 + ks2 * 16];
  *(uint4*)(dst + 8) = *(const uint4*)&tile[gl * 72 + ks2 * 16 + 8];
}

// ------------- mask all-ones flags per (bb, 16-row group, 64-col tile) -------------
__global__ __launch_bounds__(256) void mask_flags(const int* __restrict__ mask, int* __restrict__ flags) {
  int idx = blockIdx.x * 4 + (threadIdx.x >> 6);
  int lane = threadIdx.x & 63;
  int bb = idx >> 12, rg = (idx >> 5) & 127, kt = idx & 31;
  const int* base = mask + ((size_t)bb * S_ + rg * 16) * S_ + kt * 64;
  int row = lane >> 2, c0 = (lane & 3) * 16;
  int ok = 1;
  #pragma unroll
  for (int i = 0; i < 4; ++i) {
    int4 v = *(const int4*)&base[(size_t)row * S_ + c0 + i * 4];
    ok &= (v.x != 0) & (v.y != 0) & (v.z != 0) & (v.w != 0);
  }
  ok = __all(ok) ? 1 : 0;
  if (lane == 0) flags[idx] = ok;
}

// ------------- fused QKV GEMM: A(MxK) * Wqkvt(3072xK)^T + bias; split epilogue.
//   dbuf LDS + 1 barrier/K-step (stage overlaps MFMA), bank-swizzled fragments. -------------
__global__ __launch_bounds__(256) void gemm_qkv(const u16* __restrict__ A, const u16* __restrict__ Bt,
                                                const float* __restrict__ bias,
                                                u16* __restrict__ Qb, u16* __restrict__ KVb, int K) {
  __shared__ u16 As[2][128 * 32];
  __shared__ u16 Bs[2][128 * 32];
  int nbx = gridDim.x;
  int bid = blockIdx.y * nbx + blockIdx.x;
  int chunk = (nbx * gridDim.y) >> 3;
  int swz = (bid & 7) * chunk + (bid >> 3);
  int n0 = (swz % nbx) * 128, m0 = (swz / nbx) * 128;
  int t = threadIdx.x;
  int w = t >> 6, lane = t & 63, c = lane & 15, q = lane >> 4;
  int wm = w & 1, wn = w >> 1;
  int r0 = t >> 2;
  int kcs = ((t & 3) ^ ((t >> 3) & 3)) * 8;    // pre-swizzled source chunk
  const u16* Ag0 = A  + (size_t)(m0 + r0) * K + kcs;
  const u16* Ag1 = A  + (size_t)(m0 + 64 + r0) * K + kcs;
  const u16* Bg0 = Bt + (size_t)(n0 + r0) * K + kcs;
  const u16* Bg1 = Bt + (size_t)(n0 + 64 + r0) * K + kcs;
  int roff = (q ^ ((c >> 1) & 3)) * 8;         // swizzled read chunk
  f32x4 acc[4][4] = {};
  async16(Ag0, &As[0][t * 8]);
  async16(Ag1, &As[0][2048 + t * 8]);
  async16(Bg0, &Bs[0][t * 8]);
  async16(Bg1, &Bs[0][2048 + t * 8]);
  for (int k0 = 0; k0 < K; k0 += 32) {
    int cur = (k0 >> 5) & 1;
    __syncthreads();   // implicit vmcnt(0) drain: buf[cur] staged, buf[cur^1] free
    if (k0 + 32 < K) {
      async16(Ag0 + k0 + 32, &As[cur ^ 1][t * 8]);
      async16(Ag1 + k0 + 32, &As[cur ^ 1][2048 + t * 8]);
      async16(Bg0 + k0 + 32, &Bs[cur ^ 1][t * 8]);
      async16(Bg1 + k0 + 32, &Bs[cur ^ 1][2048 + t * 8]);
    }
    short8 af[4], bf[4];
    #pragma unroll
    for (int i = 0; i < 4; ++i) {
      af[i] = *(const short8*)&As[cur][(wm * 64 + i * 16 + c) * 32 + roff];
      bf[i] = *(const short8*)&Bs[cur][(wn * 64 + i * 16 + c) * 32 + roff];
    }
    #pragma unroll
    for (int i = 0; i < 4; ++i)
      #pragma unroll
      for (int j = 0; j < 4; ++j)
        acc[i][j] = __builtin_amdgcn_mfma_f32_16x16x32_bf16(af[i], bf[j], acc[i][j], 0, 0, 0);
  }
  int isq = (n0 < 2048);           // block-uniform
  #pragma unroll
  for (int i = 0; i < 4; ++i) {
    int mrow_base = m0 + wm * 64 + i * 16 + q * 4;
    #pragma unroll
    for (int j = 0; j < 4; ++j) {
      int coln = n0 + wn * 64 + j * 16 + c;
      float bv = bias[coln];
      #pragma unroll
      for (int r = 0; r < 4; ++r) {
        float v = acc[i][j][r] + bv;
        if (isq) Qb[(size_t)(mrow_base + r) * E_ + coln] = f2bf(v * QSCL);
        else     KVb[(size_t)(mrow_base + r) * KVLD_ + coln - 2048] = f2bf(v);
      }
    }
  }
}

// ------------- O-proj GEMM: C(MxN f32) = A(MxK) * Bt(NxK)^T + bias. -------------
__global__ __launch_bounds__(256) void gemm_k(const u16* __restrict__ A, const u16* __restrict__ Bt,
                                              const float* __restrict__ bias, float* __restrict__ Cout,
                                              int M, int N, int K) {
  __shared__ u16 As[2][128 * 32];
  __shared__ u16 Bs[2][128 * 32];
  int nbx = gridDim.x;
  int bid = blockIdx.y * nbx + blockIdx.x;
  int chunk = (nbx * gridDim.y) >> 3;
  int swz = (bid & 7) * chunk + (bid >> 3);
  int n0 = (swz % nbx) * 128, m0 = (swz / nbx) * 128;
  int t = threadIdx.x;
  int w = t >> 6, lane = t & 63, c = lane & 15, q = lane >> 4;
  int wm = w & 1, wn = w >> 1;
  int r0 = t >> 2;
  int kcs = ((t & 3) ^ ((t >> 3) & 3)) * 8;
  const u16* Ag0 = A  + (size_t)(m0 + r0) * K + kcs;
  const u16* Ag1 = A  + (size_t)(m0 + 64 + r0) * K + kcs;
  const u16* Bg0 = Bt + (size_t)(n0 + r0) * K + kcs;
  const u16* Bg1 = Bt + (size_t)(n0 + 64 + r0) * K + kcs;
  int roff = (q ^ ((c >> 1) & 3)) * 8;
  f32x4 acc[4][4] = {};
  async16(Ag0, &As[0][t * 8]);
  async16(Ag1, &As[0][2048 + t * 8]);
  async16(Bg0, &Bs[0][t * 8]);
  async16(Bg1, &Bs[0][2048 + t * 8]);
  for (int k0 = 0; k0 < K; k0 += 32) {
    int cur = (k0 >> 5) & 1;
    __syncthreads();
    if (k0 + 32 < K) {
      async16(Ag0 + k0 + 32, &As[cur ^ 1][t * 8]);
      async16(Ag1 + k0 + 32, &As[cur ^ 1][2048 + t * 8]);
      async16(Bg0 + k0 + 32, &Bs[cur ^ 1][t * 8]);
      async16(Bg1 + k0 + 32, &Bs[cur ^ 1][2048 + t * 8]);
    }
    short8 af[4], bf[4];
    #pragma unroll
    for (int i = 0; i < 4; ++i) {
      af[i] = *(const short8*)&As[cur][(wm * 64 + i * 16 + c) * 32 + roff];
      bf[i] = *(const short8*)&Bs[cur][(wn * 64 + i * 16 + c) * 32 + roff];
    }
    #pragma unroll
    for (int i = 0; i < 4; ++i)
      #pragma unroll
      for (int j = 0; j < 4; ++j)
        acc[i][j] = __builtin_amdgcn_mfma_f32_16x16x32_bf16(af[i], bf[j], acc[i][j], 0, 0, 0);
  }
  #pragma unroll
  for (int i = 0; i < 4; ++i) {
    int mrow_base = m0 + wm * 64 + i * 16 + q * 4;
    #pragma unroll
    for (int j = 0; j < 4; ++j) {
      int coln = n0 + wn * 64 + j * 16 + c;
      float bv = bias[coln];
      #pragma unroll
      for (int r = 0; r < 4; ++r)
        Cout[(size_t)(mrow_base + r) * N + coln] = acc[i][j][r] + bv;
    }
  }
}

// ------------- flash attention: 128 q-rows/block, 8 waves x 16 rows (16x16x32).
//   K in LDS (dbuf, 1 barrier/tile). V-fragments in REGISTERS, prefetched one
//   full tile ahead from global Vtg (T14 issue-early/consume-late: ~500cy lead
//   covers L2 latency; 8 waves read identical addrs -> L1-served after 1st).
//   LDS = 32K K + 16K P = 48KB; launch_bounds(512,4) pins 2 blocks/CU. -------------
__global__ __launch_bounds__(512, 4) void attn_k(const u16* __restrict__ Q, const u16* __restrict__ KVb,
                                                 const u16* __restrict__ Vtg, const int* __restrict__ mask,
                                                 const int* __restrict__ mflags, u16* __restrict__ O) {
  __shared__ u16 Ks[2][64 * 128]; // swizzled: phys chunk (row*16 + (kc ^ (row&15)))
  __shared__ u16 Ps[8 * 16 * 64]; // per-wave private (2KB each); permuted cols, swizzled
  int bid = blockIdx.x;
  int mt = bid & 15, h = (bid >> 4) & 15, bb = bid >> 8;
  int g = h & 3;                  // jnp.tile => head h uses group h % G
  int t = threadIdx.x, w = t >> 6, lane = t & 63, c = lane & 15, q = lane >> 4;
  int m0 = mt * 128;

  const u16* Qbase  = Q   + (size_t)(bb * S_ + m0) * E_ + h * HD_;
  const u16* Kbase  = KVb + (size_t)bb * S_ * KVLD_ + g * HD_;
  const u16* Vtbase = Vtg + (size_t)(bb * G_ + g) * HD_ * S_;

  // K staging addresses (512 threads: 32 K-rows per async round)
  int krow0 = t >> 4;                         // 0..31
  int kkc   = ((t & 15) ^ (krow0 & 15)) * 8;
  const u16* Kst = Kbase + (size_t)krow0 * KVLD_ + kkc;

  // V-fragment global base: lane (c,q) reads 16B at row (d*16+c), phys col (ks*4+q)*8
  const u16* Vl = Vtbase + (size_t)c * S_ + q * 8;

  // P LDS addresses: write 4 rows (b64 each), read 2 chunks (b128)
  int pwa[4], pra[2];
  #pragma unroll
  for (int r = 0; r < 4; ++r) {
    int row = q * 4 + r;
    pwa[r] = w * 1024 + row * 64 + (((c >> 1) ^ (row & 7)) * 8) + (c & 1) * 4;
  }
  #pragma unroll
  for (int ks = 0; ks < 2; ++ks)
    pra[ks] = w * 1024 + c * 64 + (((ks * 4 + q) ^ (c & 7)) * 8);

  // Q fragments in registers (pre-scaled by QSCL); wave w owns rows [w*16, w*16+16)
  short8 aq[4];
  #pragma unroll
  for (int k0 = 0; k0 < 4; ++k0)
    aq[k0] = *(const short8*)&Qbase[(size_t)(w * 16 + c) * E_ + k0 * 32 + q * 8];

  const short8 ones = {(short)0x3F80, (short)0x3F80, (short)0x3F80, (short)0x3F80,
                       (short)0x3F80, (short)0x3F80, (short)0x3F80, (short)0x3F80};

  f32x4 Oa[8] = {};
  f32x4 lacc = {};
  short8 vr[16];   // V B-fragments for the CURRENT tile (prefetched)

  // prologue: stage K tile 0; load V tile 0 into registers
  #pragma unroll
  for (int p = 0; p < 2; ++p)
    async16(Kst + (size_t)(p * 32) * KVLD_, &Ks[0][p * 4096 + t * 8]);
  #pragma unroll
  for (int d = 0; d < 8; ++d)
    #pragma unroll
    for (int ks = 0; ks < 2; ++ks)
      vr[d * 2 + ks] = *(const short8*)&Vl[(size_t)(d * 16) * S_ + ks * 32];

  for (int kv0 = 0; kv0 < S_; kv0 += 64) {
    int cur = (kv0 >> 6) & 1;
    // single barrier per tile: drain guarantees Ks[cur] staged and Ks[cur^1] free
    __syncthreads();
    if (kv0 + 64 < S_) {           // prefetch next K tile into the other buffer
      #pragma unroll
      for (int p = 0; p < 2; ++p)
        async16(Kst + (size_t)(kv0 + 64 + p * 32) * KVLD_, &Ks[cur ^ 1][p * 4096 + t * 8]);
    }
    const u16* K_ = Ks[cur];

    // QK^T (log2 domain)
    f32x4 sc[4] = {};
    #pragma unroll
    for (int k0 = 0; k0 < 4; ++k0) {
      short8 bk[4];
      #pragma unroll
      for (int ns = 0; ns < 4; ++ns)
        bk[ns] = *(const short8*)&K_[(ns * 16 + c) * 128 + (((k0 * 4 + q) ^ c) * 8)];
      #pragma unroll
      for (int ns = 0; ns < 4; ++ns)
        sc[ns] = __builtin_amdgcn_mfma_f32_16x16x32_bf16(aq[k0], bk[ns], sc[ns], 0, 0, 0);
    }
    // rare mask path
    {
      int flag = mflags[bb * 4096 + (mt * 8 + w) * 32 + (kv0 >> 6)];
      if (!flag) {
        #pragma unroll
        for (int r = 0; r < 4; ++r) {
          int qrow = m0 + w * 16 + q * 4 + r;
          const int* mrow = mask + ((size_t)bb * S_ + qrow) * S_ + kv0;
          #pragma unroll
          for (int ns = 0; ns < 4; ++ns)
            if (mrow[ns * 16 + c] == 0) sc[ns][r] = MASKED_L2;
        }
      }
    }
    // p = exp2(sc); pack bf16 (round-half-up), 4 permuted cols/row
    #pragma unroll
    for (int r = 0; r < 4; ++r) {
      u32 u[4];
      #pragma unroll
      for (int ns = 0; ns < 4; ++ns) {
        float p = __builtin_amdgcn_exp2f(sc[ns][r]);
        u[ns] = __float_as_uint(p) + 0x8000u;
      }
      uint2 pk;
      pk.x = __builtin_amdgcn_perm(u[1], u[0], 0x07060302);
      pk.y = __builtin_amdgcn_perm(u[3], u[2], 0x07060302);
      *(uint2*)&Ps[pwa[r]] = pk;
    }
    __asm__ volatile("" ::: "memory");   // Ps is wave-private: LDS pipe is in-order per wave
    // PV + row-sums; V B-frags from registers (prefetched last iteration)
    #pragma unroll
    for (int ks = 0; ks < 2; ++ks) {
      short8 ap = *(const short8*)&Ps[pra[ks]];
      lacc = __builtin_amdgcn_mfma_f32_16x16x32_bf16(ap, ones, lacc, 0, 0, 0);
      #pragma unroll
      for (int d = 0; d < 8; ++d)
        Oa[d] = __builtin_amdgcn_mfma_f32_16x16x32_bf16(ap, vr[d * 2 + ks], Oa[d], 0, 0, 0);
    }
    // issue V loads for the NEXT tile (WAR on vr orders them after PV reads);
    // consumed after barrier + QK^T + softmax of the next iteration (~500cy lead)
    if (kv0 + 64 < S_) {
      const u16* Vn = Vl + kv0 + 64;
      #pragma unroll
      for (int d = 0; d < 8; ++d)
        #pragma unroll
        for (int ks = 0; ks < 2; ++ks)
          vr[d * 2 + ks] = *(const short8*)&Vn[(size_t)(d * 16) * S_ + ks * 32];
    }
  }
  {
    float inv[4];
    #pragma unroll
    for (int r = 0; r < 4; ++r) inv[r] = 1.0f / lacc[r];
    #pragma unroll
    for (int d = 0; d < 8; ++d)
      #pragma unroll
      for (int r = 0; r < 4; ++r) {
        size_t off = (size_t)(bb * S_ + m0 + w * 16 + q * 4 + r) * E_ + h * HD_ + d * 16 + c;
        O[off] = f2bf(Oa[d][r] * inv[r]);
      }
  }
}

extern "C" void kernel_launch(void* const* d_in, const int* in_sizes, int n_in,
                              void* d_out, int out_size, void* d_ws, size_t ws_size,
                              hipStream_t stream) {
  const float* x    = (const float*)d_in[0];
  const int*   mask = (const int*)d_in[1];
  const float* Wq   = (const float*)d_in[2];
  const float* bq   = (const float*)d_in[3];
  const float* Wk   = (const float*)d_in[4];
  const float* bk   = (const float*)d_in[5];
  const float* Wv   = (const float*)d_in[6];
  const float* bv   = (const float*)d_in[7];
  const float* Wo   = (const float*)d_in[8];
  const float* bo   = (const float*)d_in[9];
  float* out = (float*)d_out;

  char* ws = (char*)d_ws;
  u16* xb    = (u16*)ws; ws += (size_t)M_ * E_ * 2;
  u16* Wqkvt = (u16*)ws; ws += (size_t)QKVN_ * E_ * 2;
  u16* Wot   = (u16*)ws; ws += (size_t)E_ * E_ * 2;
  u16* Qb    = (u16*)ws; ws += (size_t)M_ * E_ * 2;
  u16* KVb   = (u16*)ws; ws += (size_t)M_ * KVLD_ * 2;
  u16* Ob    = (u16*)ws; ws += (size_t)M_ * E_ * 2;
  u16* Vtg   = (u16*)ws; ws += (size_t)B_ * G_ * HD_ * S_ * 2;
  int* mfl   = (int*)ws; ws += (size_t)B_ * 128 * 32 * 4;
  float* bqkv = (float*)ws; ws += QKVN_ * 4;

  cast_f32_bf16<<<(M_ * E_ / 4 + 255) / 256, 256, 0, stream>>>(x, xb, M_ * E_ / 4);
  transpose_cast<<<dim3(E_ / 64,  E_ / 64), 256, 0, stream>>>(Wq, Wqkvt, E_, E_);
  transpose_cast<<<dim3(GD_ / 64, E_ / 64), 256, 0, stream>>>(Wk, Wqkvt + (size_t)2048 * E_, E_, GD_);
  transpose_cast<<<dim3(GD_ / 64, E_ / 64), 256, 0, stream>>>(Wv, Wqkvt + (size_t)2560 * E_, E_, GD_);
  transpose_cast<<<dim3(E_ / 64,  E_ / 64), 256, 0, stream>>>(Wo, Wot, E_, E_);
  concat_bias3<<<QKVN_ / 256, 256, 0, stream>>>(bq, bk, bv, bqkv);
  mask_flags<<<B_ * 128 * 32 / 4, 256, 0, stream>>>(mask, mfl);

  gemm_qkv<<<dim3(QKVN_ / 128, M_ / 128), 256, 0, stream>>>(xb, Wqkvt, bqkv, Qb, KVb, E_);
  transpose_v<<<dim3(M_ / 64, GD_ / 64), 256, 0, stream>>>(KVb, Vtg);

  attn_k<<<B_ * H_ * (S_ / 128), 512, 0, stream>>>(Qb, KVb, Vtg, mask, mfl, Ob);

  gemm_k<<<dim3(E_ / 128, M_ / 128), 256, 0, stream>>>(Ob, Wot, bo, out, M_, E_, E_);
}

// Round 7
// 535.169 us; speedup vs baseline: 1.3408x; 1.3408x over previous
//
#include <hip/hip_runtime.h>

#define B_ 2
#define S_ 2048
#define E_ 2048
#define H_ 16
#define G_ 4
#define HD_ 128
#define GD_ 512
#define KVLD_ 1024
#define QKVN_ 3072
#define M_ (B_*S_)   // 4096

using u16 = unsigned short;
using u32 = unsigned int;
typedef __attribute__((ext_vector_type(8))) short short8;
typedef __attribute__((ext_vector_type(4))) float f32x4;

// scale * log2(e), folded into Q so scores come out in log2 domain
#define QSCL 0.12751891114f   // (1/sqrt(128)) * 1.4426950408889634
#define MASKED_L2 (-14427.0f) // -10000 * log2(e)

__device__ __forceinline__ u16 f2bf(float f) {
  union { float f; unsigned u; } v; v.f = f;
  unsigned r = v.u + 0x7fff + ((v.u >> 16) & 1);  // RNE
  return (u16)(r >> 16);
}

__device__ __forceinline__ void async16(const void* g, void* l) {
  __builtin_amdgcn_global_load_lds((const __attribute__((address_space(1))) unsigned int*)g,
                                   (__attribute__((address_space(3))) unsigned int*)l, 16, 0, 0);
}

// ---------------- elementwise f32 -> bf16 cast (x) ----------------
__global__ __launch_bounds__(256) void cast_f32_bf16(const float* __restrict__ in,
                                                     u16* __restrict__ out, int n4) {
  int i = blockIdx.x * 256 + threadIdx.x;
  if (i >= n4) return;
  float4 v = ((const float4*)in)[i];
  union { u16 o[4]; uint2 u; } pk;
  pk.o[0] = f2bf(v.x); pk.o[1] = f2bf(v.y); pk.o[2] = f2bf(v.z); pk.o[3] = f2bf(v.w);
  *(uint2*)(out + (size_t)i * 4) = pk.u;
}

__global__ __launch_bounds__(256) void concat_bias3(const float* __restrict__ a,
                                                    const float* __restrict__ b,
                                                    const float* __restrict__ c,
                                                    float* __restrict__ o) {
  int t = blockIdx.x * 256 + threadIdx.x;
  if (t < 2048) o[t] = a[t];
  else if (t < 2560) o[t] = b[t - 2048];
  else if (t < 3072) o[t] = c[t - 2560];
}

// ------------- W (KxN f32) -> Wt (NxK bf16) transpose-cast -------------
__global__ __launch_bounds__(256) void transpose_cast(const float* __restrict__ W,
                                                      u16* __restrict__ Wt, int K, int N) {
  __shared__ u16 tile[64 * 72];
  int n0 = blockIdx.x * 64, k0 = blockIdx.y * 64;
  int t = threadIdx.x;
  int row = t >> 2;       // k_local 0..63
  int seg = t & 3;        // 16 f32 each
  const float* src = W + (size_t)(k0 + row) * N + n0 + seg * 16;
  #pragma unroll
  for (int i = 0; i < 4; ++i) {
    float4 v = *(const float4*)(src + i * 4);
    int nl = seg * 16 + i * 4;
    tile[(nl + 0) * 72 + row] = f2bf(v.x);
    tile[(nl + 1) * 72 + row] = f2bf(v.y);
    tile[(nl + 2) * 72 + row] = f2bf(v.z);
    tile[(nl + 3) * 72 + row] = f2bf(v.w);
  }
  __syncthreads();
  int nl = t >> 2, s2 = t & 3;   // 16 bf16 per thread
  u16* dst = Wt + (size_t)(n0 + nl) * K + k0 + s2 * 16;
  *(uint4*)dst       = *(const uint4*)&tile[nl * 72 + s2 * 16];
  *(uint4*)(dst + 8) = *(const uint4*)&tile[nl * 72 + s2 * 16 + 8];
}

// ------------- V (from KVb, cols 512..1023) -> Vtg[(bb*G+g)*HD+n][S] with
// kv permuted within each 32-block: phys = (kv&15)*2 + (kv>>4)  (matches the
// P u32 pack: pair (kv=c, kv=c+16) -> phys {2c, 2c+1}) -------------
__global__ __launch_bounds__(256) void transpose_v(const u16* __restrict__ KVb, u16* __restrict__ Vtg) {
  __shared__ u16 tile[64 * 72];
  int kv0 = blockIdx.x * 64;      // over M_
  int gn0 = blockIdx.y * 64;      // over GD_
  int t = threadIdx.x;
  int row = t >> 2, seg = t & 3;
  int r32 = row & 31;
  int prow = (row & 32) + (r32 & 15) * 2 + (r32 >> 4);   // per-32-block kv permutation
  const u16* src = KVb + (size_t)(kv0 + row) * KVLD_ + 512 + gn0 + seg * 16;
  union { uint4 v; u16 s[8]; } a, b;
  a.v = *(const uint4*)src; b.v = *(const uint4*)(src + 8);
  #pragma unroll
  for (int j = 0; j < 8; ++j) tile[(seg * 16 + j) * 72 + prow] = a.s[j];
  #pragma unroll
  for (int j = 0; j < 8; ++j) tile[(seg * 16 + 8 + j) * 72 + prow] = b.s[j];
  __syncthreads();
  int gl = t >> 2, ks2 = t & 3;
  int bb = kv0 >> 11;
  int s0 = kv0 & 2047;
  int gn = gn0 + gl;
  u16* dst = Vtg + (size_t)(bb * 512 + gn) * S_ + s0 + ks2 * 16;
  *(uint4*)dst       = *(const uint4*)&tile[gl * 72 + ks2 * 16];
  *(uint4*)(dst + 8) = *(const uint4*)&tile[gl * 72 + ks2 * 16 + 8];
}

// ------------- mask all-ones flags per (bb, 16-row group, 64-col tile) -------------
__global__ __launch_bounds__(256) void mask_flags(const int* __restrict__ mask, int* __restrict__ flags) {
  int idx = blockIdx.x * 4 + (threadIdx.x >> 6);
  int lane = threadIdx.x & 63;
  int bb = idx >> 12, rg = (idx >> 5) & 127, kt = idx & 31;
  const int* base = mask + ((size_t)bb * S_ + rg * 16) * S_ + kt * 64;
  int row = lane >> 2, c0 = (lane & 3) * 16;
  int ok = 1;
  #pragma unroll
  for (int i = 0; i < 4; ++i) {
    int4 v = *(const int4*)&base[(size_t)row * S_ + c0 + i * 4];
    ok &= (v.x != 0) & (v.y != 0) & (v.z != 0) & (v.w != 0);
  }
  ok = __all(ok) ? 1 : 0;
  if (lane == 0) flags[idx] = ok;
}

// ------------- fused QKV GEMM: A(MxK) * Wqkvt(3072xK)^T + bias; split epilogue.
//   dbuf LDS + 1 barrier/K-step (stage overlaps MFMA), bank-swizzled fragments. -------------
__global__ __launch_bounds__(256) void gemm_qkv(const u16* __restrict__ A, const u16* __restrict__ Bt,
                                                const float* __restrict__ bias,
                                                u16* __restrict__ Qb, u16* __restrict__ KVb, int K) {
  __shared__ u16 As[2][128 * 32];
  __shared__ u16 Bs[2][128 * 32];
  int nbx = gridDim.x;
  int bid = blockIdx.y * nbx + blockIdx.x;
  int chunk = (nbx * gridDim.y) >> 3;
  int swz = (bid & 7) * chunk + (bid >> 3);
  int n0 = (swz % nbx) * 128, m0 = (swz / nbx) * 128;
  int t = threadIdx.x;
  int w = t >> 6, lane = t & 63, c = lane & 15, q = lane >> 4;
  int wm = w & 1, wn = w >> 1;
  int r0 = t >> 2;
  int kcs = ((t & 3) ^ ((t >> 3) & 3)) * 8;    // pre-swizzled source chunk
  const u16* Ag0 = A  + (size_t)(m0 + r0) * K + kcs;
  const u16* Ag1 = A  + (size_t)(m0 + 64 + r0) * K + kcs;
  const u16* Bg0 = Bt + (size_t)(n0 + r0) * K + kcs;
  const u16* Bg1 = Bt + (size_t)(n0 + 64 + r0) * K + kcs;
  int roff = (q ^ ((c >> 1) & 3)) * 8;         // swizzled read chunk
  f32x4 acc[4][4] = {};
  async16(Ag0, &As[0][t * 8]);
  async16(Ag1, &As[0][2048 + t * 8]);
  async16(Bg0, &Bs[0][t * 8]);
  async16(Bg1, &Bs[0][2048 + t * 8]);
  for (int k0 = 0; k0 < K; k0 += 32) {
    int cur = (k0 >> 5) & 1;
    __syncthreads();   // implicit vmcnt(0) drain: buf[cur] staged, buf[cur^1] free
    if (k0 + 32 < K) {
      async16(Ag0 + k0 + 32, &As[cur ^ 1][t * 8]);
      async16(Ag1 + k0 + 32, &As[cur ^ 1][2048 + t * 8]);
      async16(Bg0 + k0 + 32, &Bs[cur ^ 1][t * 8]);
      async16(Bg1 + k0 + 32, &Bs[cur ^ 1][2048 + t * 8]);
    }
    short8 af[4], bf[4];
    #pragma unroll
    for (int i = 0; i < 4; ++i) {
      af[i] = *(const short8*)&As[cur][(wm * 64 + i * 16 + c) * 32 + roff];
      bf[i] = *(const short8*)&Bs[cur][(wn * 64 + i * 16 + c) * 32 + roff];
    }
    #pragma unroll
    for (int i = 0; i < 4; ++i)
      #pragma unroll
      for (int j = 0; j < 4; ++j)
        acc[i][j] = __builtin_amdgcn_mfma_f32_16x16x32_bf16(af[i], bf[j], acc[i][j], 0, 0, 0);
  }
  int isq = (n0 < 2048);           // block-uniform
  #pragma unroll
  for (int i = 0; i < 4; ++i) {
    int mrow_base = m0 + wm * 64 + i * 16 + q * 4;
    #pragma unroll
    for (int j = 0; j < 4; ++j) {
      int coln = n0 + wn * 64 + j * 16 + c;
      float bv = bias[coln];
      #pragma unroll
      for (int r = 0; r < 4; ++r) {
        float v = acc[i][j][r] + bv;
        if (isq) Qb[(size_t)(mrow_base + r) * E_ + coln] = f2bf(v * QSCL);
        else     KVb[(size_t)(mrow_base + r) * KVLD_ + coln - 2048] = f2bf(v);
      }
    }
  }
}

// ------------- O-proj GEMM: C(MxN f32) = A(MxK) * Bt(NxK)^T + bias. -------------
__global__ __launch_bounds__(256) void gemm_k(const u16* __restrict__ A, const u16* __restrict__ Bt,
                                              const float* __restrict__ bias, float* __restrict__ Cout,
                                              int M, int N, int K) {
  __shared__ u16 As[2][128 * 32];
  __shared__ u16 Bs[2][128 * 32];
  int nbx = gridDim.x;
  int bid = blockIdx.y * nbx + blockIdx.x;
  int chunk = (nbx * gridDim.y) >> 3;
  int swz = (bid & 7) * chunk + (bid >> 3);
  int n0 = (swz % nbx) * 128, m0 = (swz / nbx) * 128;
  int t = threadIdx.x;
  int w = t >> 6, lane = t & 63, c = lane & 15, q = lane >> 4;
  int wm = w & 1, wn = w >> 1;
  int r0 = t >> 2;
  int kcs = ((t & 3) ^ ((t >> 3) & 3)) * 8;
  const u16* Ag0 = A  + (size_t)(m0 + r0) * K + kcs;
  const u16* Ag1 = A  + (size_t)(m0 + 64 + r0) * K + kcs;
  const u16* Bg0 = Bt + (size_t)(n0 + r0) * K + kcs;
  const u16* Bg1 = Bt + (size_t)(n0 + 64 + r0) * K + kcs;
  int roff = (q ^ ((c >> 1) & 3)) * 8;
  f32x4 acc[4][4] = {};
  async16(Ag0, &As[0][t * 8]);
  async16(Ag1, &As[0][2048 + t * 8]);
  async16(Bg0, &Bs[0][t * 8]);
  async16(Bg1, &Bs[0][2048 + t * 8]);
  for (int k0 = 0; k0 < K; k0 += 32) {
    int cur = (k0 >> 5) & 1;
    __syncthreads();
    if (k0 + 32 < K) {
      async16(Ag0 + k0 + 32, &As[cur ^ 1][t * 8]);
      async16(Ag1 + k0 + 32, &As[cur ^ 1][2048 + t * 8]);
      async16(Bg0 + k0 + 32, &Bs[cur ^ 1][t * 8]);
      async16(Bg1 + k0 + 32, &Bs[cur ^ 1][2048 + t * 8]);
    }
    short8 af[4], bf[4];
    #pragma unroll
    for (int i = 0; i < 4; ++i) {
      af[i] = *(const short8*)&As[cur][(wm * 64 + i * 16 + c) * 32 + roff];
      bf[i] = *(const short8*)&Bs[cur][(wn * 64 + i * 16 + c) * 32 + roff];
    }
    #pragma unroll
    for (int i = 0; i < 4; ++i)
      #pragma unroll
      for (int j = 0; j < 4; ++j)
        acc[i][j] = __builtin_amdgcn_mfma_f32_16x16x32_bf16(af[i], bf[j], acc[i][j], 0, 0, 0);
  }
  #pragma unroll
  for (int i = 0; i < 4; ++i) {
    int mrow_base = m0 + wm * 64 + i * 16 + q * 4;
    #pragma unroll
    for (int j = 0; j < 4; ++j) {
      int coln = n0 + wn * 64 + j * 16 + c;
      float bv = bias[coln];
      #pragma unroll
      for (int r = 0; r < 4; ++r)
        Cout[(size_t)(mrow_base + r) * N + coln] = acc[i][j][r] + bv;
    }
  }
}

// ------------- flash attention: 128 q-rows/block, 8 waves x 16 rows (16x16x32),
//   kv-tile = 32. K in LDS (dbuf, 1 barrier/tile, R2-verified swizzle).
//   V-fragments in REGISTERS (vr[8] = 32 VGPRs), prefetched one full tile ahead
//   (issued after PV(t), drained by barrier(t+1) -> full-tile latency slack).
//   XCD-grouped grid: bid&7 = bb*4+g so each XCD's L2 holds one (bb,g) K+V set.
//   LDS = 16K K + 8K P = 24KB; no launch-bounds cap (VGPR ~100 -> 4 waves/SIMD). -------------
__global__ __launch_bounds__(512) void attn_k(const u16* __restrict__ Q, const u16* __restrict__ KVb,
                                              const u16* __restrict__ Vtg, const int* __restrict__ mask,
                                              const int* __restrict__ mflags, u16* __restrict__ O) {
  __shared__ u16 Ks[2][32 * 128]; // swizzled: phys chunk = kc ^ (row&15) (dest linear, src pre-XORed)
  __shared__ u16 Ps[8 * 16 * 32]; // per-wave 1KB: [row][32 kv-phys]; 16B-chunk swz ^ ((row>>1)&3)
  int bid = blockIdx.x;
  int combo = bid & 7;            // bb*4 + g  -> same-XCD blocks share K/V in L2
  int bb = combo >> 2, g = combo & 3;
  int idx = bid >> 3;
  int h  = (idx & 3) * 4 + g;     // h % G == g  (jnp.tile)
  int mt = idx >> 2;              // 0..15
  int t = threadIdx.x, w = t >> 6, lane = t & 63, c = lane & 15, q = lane >> 4;
  int m0 = mt * 128;

  const u16* Qbase  = Q   + (size_t)(bb * S_ + m0) * E_ + h * HD_;
  const u16* Kbase  = KVb + (size_t)bb * S_ * KVLD_ + g * HD_;
  const u16* Vtbase = Vtg + (size_t)(bb * G_ + g) * HD_ * S_;

  // K staging (512 threads stage the whole 32x128 tile in ONE async round)
  int krow0 = t >> 4;                         // 0..31
  int kkc   = ((t & 15) ^ (krow0 & 15)) * 8;  // pre-swizzled source chunk
  const u16* Kst = Kbase + (size_t)krow0 * KVLD_ + kkc;

  // V-fragment global base: lane (c,q), d-block d: 16B at row (d*16+c), phys col q*8
  const u16* Vl = Vtbase + (size_t)c * S_ + q * 8;

  // P LDS addresses (u16 units, per-wave 512 u16).
  // write: u32 of pair (kv=c, kv=c+16) at row q*4+r, logical u32 col c;
  //        phys 16B-chunk = (c>>2) ^ ((row>>1)&3), within-chunk u32 = c&3
  int pwa[4];
  #pragma unroll
  for (int r = 0; r < 4; ++r) {
    int row = q * 4 + r;
    pwa[r] = w * 512 + row * 32 + (((c >> 2) ^ ((row >> 1) & 3)) << 3) + ((c & 3) << 1);
  }
  // read: b128 at row c, logical chunk q -> phys chunk q ^ ((c>>1)&3)
  int pra = w * 512 + c * 32 + ((q ^ ((c >> 1) & 3)) << 3);

  // Q fragments in registers (pre-scaled by QSCL); wave w owns rows [w*16, w*16+16)
  short8 aq[4];
  #pragma unroll
  for (int k0 = 0; k0 < 4; ++k0)
    aq[k0] = *(const short8*)&Qbase[(size_t)(w * 16 + c) * E_ + k0 * 32 + q * 8];

  const short8 ones = {(short)0x3F80, (short)0x3F80, (short)0x3F80, (short)0x3F80,
                       (short)0x3F80, (short)0x3F80, (short)0x3F80, (short)0x3F80};

  f32x4 Oa[8] = {};
  f32x4 lacc = {};
  short8 vr[8];   // V B-fragments for the CURRENT tile (prefetched one tile ahead)

  // prologue: stage K tile 0; load V tile 0 into registers
  async16(Kst, &Ks[0][t * 8]);
  #pragma unroll
  for (int d = 0; d < 8; ++d)
    vr[d] = *(const short8*)&Vl[(size_t)(d * 16) * S_];

  for (int kv0 = 0; kv0 < S_; kv0 += 32) {
    int cur = (kv0 >> 5) & 1;
    // single barrier per tile: drain guarantees Ks[cur] staged, Ks[cur^1] free,
    // and vr loads (issued last iteration) complete.
    __syncthreads();
    if (kv0 + 32 < S_)
      async16(Kst + (size_t)(kv0 + 32) * KVLD_, &Ks[cur ^ 1][t * 8]);
    const u16* K_ = Ks[cur];

    // QK^T (log2 domain): 16 rows x 32 cols
    f32x4 sc[2] = {};
    #pragma unroll
    for (int k0 = 0; k0 < 4; ++k0) {
      short8 bk0 = *(const short8*)&K_[(c) * 128 + (((k0 * 4 + q) ^ c) * 8)];
      short8 bk1 = *(const short8*)&K_[(16 + c) * 128 + (((k0 * 4 + q) ^ c) * 8)];
      sc[0] = __builtin_amdgcn_mfma_f32_16x16x32_bf16(aq[k0], bk0, sc[0], 0, 0, 0);
      sc[1] = __builtin_amdgcn_mfma_f32_16x16x32_bf16(aq[k0], bk1, sc[1], 0, 0, 0);
    }
    // rare mask path (flag granularity is 64 cols; covers this 32-half too)
    {
      int flag = mflags[bb * 4096 + (mt * 8 + w) * 32 + (kv0 >> 6)];
      if (!flag) {
        #pragma unroll
        for (int r = 0; r < 4; ++r) {
          int qrow = m0 + w * 16 + q * 4 + r;
          const int* mrow = mask + ((size_t)bb * S_ + qrow) * S_ + kv0;
          if (mrow[c] == 0)      sc[0][r] = MASKED_L2;
          if (mrow[16 + c] == 0) sc[1][r] = MASKED_L2;
        }
      }
    }
    // p = exp2(sc); pack pair (kv=c, kv=c+16) -> one u32 store per row
    #pragma unroll
    for (int r = 0; r < 4; ++r) {
      u32 u0 = __float_as_uint(__builtin_amdgcn_exp2f(sc[0][r])) + 0x8000u;
      u32 u1 = __float_as_uint(__builtin_amdgcn_exp2f(sc[1][r])) + 0x8000u;
      *(u32*)&Ps[pwa[r]] = __builtin_amdgcn_perm(u1, u0, 0x07060302);
    }
    __asm__ volatile("" ::: "memory");   // Ps wave-private: LDS in-order per wave
    // PV + row-sums: A = P (1 b128), B = vr (registers)
    short8 ap = *(const short8*)&Ps[pra];
    lacc = __builtin_amdgcn_mfma_f32_16x16x32_bf16(ap, ones, lacc, 0, 0, 0);
    #pragma unroll
    for (int d = 0; d < 8; ++d)
      Oa[d] = __builtin_amdgcn_mfma_f32_16x16x32_bf16(ap, vr[d], Oa[d], 0, 0, 0);
    // issue V loads for the NEXT tile (WAR on vr orders them after PV reads);
    // they complete under the next barrier + QK^T + softmax (full-tile slack)
    if (kv0 + 32 < S_) {
      const u16* Vn = Vl + kv0 + 32;
      #pragma unroll
      for (int d = 0; d < 8; ++d)
        vr[d] = *(const short8*)&Vn[(size_t)(d * 16) * S_];
    }
  }
  {
    float inv[4];
    #pragma unroll
    for (int r = 0; r < 4; ++r) inv[r] = 1.0f / lacc[r];
    #pragma unroll
    for (int d = 0; d < 8; ++d)
      #pragma unroll
      for (int r = 0; r < 4; ++r) {
        size_t off = (size_t)(bb * S_ + m0 + w * 16 + q * 4 + r) * E_ + h * HD_ + d * 16 + c;
        O[off] = f2bf(Oa[d][r] * inv[r]);
      }
  }
}

extern "C" void kernel_launch(void* const* d_in, const int* in_sizes, int n_in,
                              void* d_out, int out_size, void* d_ws, size_t ws_size,
                              hipStream_t stream) {
  const float* x    = (const float*)d_in[0];
  const int*   mask = (const int*)d_in[1];
  const float* Wq   = (const float*)d_in[2];
  const float* bq   = (const float*)d_in[3];
  const float* Wk   = (const float*)d_in[4];
  const float* bk   = (const float*)d_in[5];
  const float* Wv   = (const float*)d_in[6];
  const float* bv   = (const float*)d_in[7];
  const float* Wo   = (const float*)d_in[8];
  const float* bo   = (const float*)d_in[9];
  float* out = (float*)d_out;

  char* ws = (char*)d_ws;
  u16* xb    = (u16*)ws; ws += (size_t)M_ * E_ * 2;
  u16* Wqkvt = (u16*)ws; ws += (size_t)QKVN_ * E_ * 2;
  u16* Wot   = (u16*)ws; ws += (size_t)E_ * E_ * 2;
  u16* Qb    = (u16*)ws; ws += (size_t)M_ * E_ * 2;
  u16* KVb   = (u16*)ws; ws += (size_t)M_ * KVLD_ * 2;
  u16* Ob    = (u16*)ws; ws += (size_t)M_ * E_ * 2;
  u16* Vtg   = (u16*)ws; ws += (size_t)B_ * G_ * HD_ * S_ * 2;
  int* mfl   = (int*)ws; ws += (size_t)B_ * 128 * 32 * 4;
  float* bqkv = (float*)ws; ws += QKVN_ * 4;

  cast_f32_bf16<<<(M_ * E_ / 4 + 255) / 256, 256, 0, stream>>>(x, xb, M_ * E_ / 4);
  transpose_cast<<<dim3(E_ / 64,  E_ / 64), 256, 0, stream>>>(Wq, Wqkvt, E_, E_);
  transpose_cast<<<dim3(GD_ / 64, E_ / 64), 256, 0, stream>>>(Wk, Wqkvt + (size_t)2048 * E_, E_, GD_);
  transpose_cast<<<dim3(GD_ / 64, E_ / 64), 256, 0, stream>>>(Wv, Wqkvt + (size_t)2560 * E_, E_, GD_);
  transpose_cast<<<dim3(E_ / 64,  E_ / 64), 256, 0, stream>>>(Wo, Wot, E_, E_);
  concat_bias3<<<QKVN_ / 256, 256, 0, stream>>>(bq, bk, bv, bqkv);
  mask_flags<<<B_ * 128 * 32 / 4, 256, 0, stream>>>(mask, mfl);

  gemm_qkv<<<dim3(QKVN_ / 128, M_ / 128), 256, 0, stream>>>(xb, Wqkvt, bqkv, Qb, KVb, E_);
  transpose_v<<<dim3(M_ / 64, GD_ / 64), 256, 0, stream>>>(KVb, Vtg);

  attn_k<<<B_ * H_ * (S_ / 128), 512, 0, stream>>>(Qb, KVb, Vtg, mask, mfl, Ob);

  gemm_k<<<dim3(E_ / 128, M_ / 128), 256, 0, stream>>>(Ob, Wot, bo, out, M_, E_, E_);
}

// Round 8
// 343.192 us; speedup vs baseline: 2.0908x; 1.5594x over previous
//
#include <hip/hip_runtime.h>

#define B_ 2
#define S_ 2048
#define E_ 2048
#define H_ 16
#define G_ 4
#define HD_ 128
#define GD_ 512
#define KVLD_ 1024
#define QKVN_ 3072
#define M_ (B_*S_)   // 4096

using u16 = unsigned short;
using u32 = unsigned int;
typedef __attribute__((ext_vector_type(8))) short short8;
typedef __attribute__((ext_vector_type(4))) float f32x4;

// scale * log2(e), folded into Q so scores come out in log2 domain
#define QSCL 0.12751891114f   // (1/sqrt(128)) * 1.4426950408889634
#define MASKED_L2 (-14427.0f) // -10000 * log2(e)

__device__ __forceinline__ u16 f2bf(float f) {
  union { float f; unsigned u; } v; v.f = f;
  unsigned r = v.u + 0x7fff + ((v.u >> 16) & 1);  // RNE
  return (u16)(r >> 16);
}

__device__ __forceinline__ void async16(const void* g, void* l) {
  __builtin_amdgcn_global_load_lds((const __attribute__((address_space(1))) unsigned int*)g,
                                   (__attribute__((address_space(3))) unsigned int*)l, 16, 0, 0);
}

// ---------------- fused: f32->bf16 cast (x) + bias concat ----------------
__global__ __launch_bounds__(256) void cast_plus(const float* __restrict__ in,
                                                 u16* __restrict__ out, int n4,
                                                 const float* __restrict__ ba,
                                                 const float* __restrict__ bbk,
                                                 const float* __restrict__ bc,
                                                 float* __restrict__ bo) {
  if ((int)blockIdx.x >= (n4 + 255) / 256) {   // tail blocks: bias concat
    int t = (blockIdx.x - (n4 + 255) / 256) * 256 + threadIdx.x;
    if (t < 2048) bo[t] = ba[t];
    else if (t < 2560) bo[t] = bbk[t - 2048];
    else if (t < 3072) bo[t] = bc[t - 2560];
    return;
  }
  int i = blockIdx.x * 256 + threadIdx.x;
  if (i >= n4) return;
  float4 v = ((const float4*)in)[i];
  union { u16 o[4]; uint2 u; } pk;
  pk.o[0] = f2bf(v.x); pk.o[1] = f2bf(v.y); pk.o[2] = f2bf(v.z); pk.o[3] = f2bf(v.w);
  *(uint2*)(out + (size_t)i * 4) = pk.u;
}

// ------------- fused W transpose-cast: all 4 weights in one launch -------------
// per 64x64 tile; K = E_ for all; N varies. Block ranges:
// [0,1024) Wq -> Wqkvt+0 ; [1024,1280) Wk -> +2048*E ; [1280,1536) Wv -> +2560*E ; [1536,2560) Wo -> Wot
__global__ __launch_bounds__(256) void transpose_cast4(const float* __restrict__ Wq,
                                                       const float* __restrict__ Wk,
                                                       const float* __restrict__ Wv,
                                                       const float* __restrict__ Wo,
                                                       u16* __restrict__ Wqkvt,
                                                       u16* __restrict__ Wot) {
  __shared__ u16 tile[64 * 72];
  int b = blockIdx.x;
  const float* W; u16* Wt; int N, bx;
  if (b < 1024)      { W = Wq; Wt = Wqkvt;                     N = E_;  bx = b;        }
  else if (b < 1280) { W = Wk; Wt = Wqkvt + (size_t)2048 * E_; N = GD_; bx = b - 1024; }
  else if (b < 1536) { W = Wv; Wt = Wqkvt + (size_t)2560 * E_; N = GD_; bx = b - 1280; }
  else               { W = Wo; Wt = Wot;                       N = E_;  bx = b - 1536; }
  int nbx = N / 64;
  int n0 = (bx % nbx) * 64, k0 = (bx / nbx) * 64;
  int t = threadIdx.x;
  int row = t >> 2;       // k_local 0..63
  int seg = t & 3;        // 16 f32 each
  const float* src = W + (size_t)(k0 + row) * N + n0 + seg * 16;
  #pragma unroll
  for (int i = 0; i < 4; ++i) {
    float4 v = *(const float4*)(src + i * 4);
    int nl = seg * 16 + i * 4;
    tile[(nl + 0) * 72 + row] = f2bf(v.x);
    tile[(nl + 1) * 72 + row] = f2bf(v.y);
    tile[(nl + 2) * 72 + row] = f2bf(v.z);
    tile[(nl + 3) * 72 + row] = f2bf(v.w);
  }
  __syncthreads();
  int nl = t >> 2, s2 = t & 3;   // 16 bf16 per thread
  u16* dst = Wt + (size_t)(n0 + nl) * E_ + k0 + s2 * 16;
  *(uint4*)dst       = *(const uint4*)&tile[nl * 72 + s2 * 16];
  *(uint4*)(dst + 8) = *(const uint4*)&tile[nl * 72 + s2 * 16 + 8];
}

// ------------- V (from KVb, cols 512..1023) -> Vtg[(bb*G+g)*HD+n][S] with
// kv permuted within each 64-block: phys = (kv&15)*4 + (kv>>4) -------------
__global__ __launch_bounds__(256) void transpose_v(const u16* __restrict__ KVb, u16* __restrict__ Vtg) {
  __shared__ u16 tile[64 * 72];
  int kv0 = blockIdx.x * 64;      // over M_
  int gn0 = blockIdx.y * 64;      // over GD_
  int t = threadIdx.x;
  int row = t >> 2, seg = t & 3;
  int prow = (row & 15) * 4 + (row >> 4);   // kv permutation
  const u16* src = KVb + (size_t)(kv0 + row) * KVLD_ + 512 + gn0 + seg * 16;
  union { uint4 v; u16 s[8]; } a, b;
  a.v = *(const uint4*)src; b.v = *(const uint4*)(src + 8);
  #pragma unroll
  for (int j = 0; j < 8; ++j) tile[(seg * 16 + j) * 72 + prow] = a.s[j];
  #pragma unroll
  for (int j = 0; j < 8; ++j) tile[(seg * 16 + 8 + j) * 72 + prow] = b.s[j];
  __syncthreads();
  int gl = t >> 2, ks2 = t & 3;
  int bb = kv0 >> 11;
  int s0 = kv0 & 2047;
  int gn = gn0 + gl;
  u16* dst = Vtg + (size_t)(bb * 512 + gn) * S_ + s0 + ks2 * 16;
  *(uint4*)dst       = *(const uint4*)&tile[gl * 72 + ks2 * 16];
  *(uint4*)(dst + 8) = *(const uint4*)&tile[gl * 72 + ks2 * 16 + 8];
}

// ------------- mask all-ones flags per (bb, 16-row group, 64-col tile) -------------
__global__ __launch_bounds__(256) void mask_flags(const int* __restrict__ mask, int* __restrict__ flags) {
  int idx = blockIdx.x * 4 + (threadIdx.x >> 6);
  int lane = threadIdx.x & 63;
  int bb = idx >> 12, rg = (idx >> 5) & 127, kt = idx & 31;
  const int* base = mask + ((size_t)bb * S_ + rg * 16) * S_ + kt * 64;
  int row = lane >> 2, c0 = (lane & 3) * 16;
  int ok = 1;
  #pragma unroll
  for (int i = 0; i < 4; ++i) {
    int4 v = *(const int4*)&base[(size_t)row * S_ + c0 + i * 4];
    ok &= (v.x != 0) & (v.y != 0) & (v.z != 0) & (v.w != 0);
  }
  ok = __all(ok) ? 1 : 0;
  if (lane == 0) flags[idx] = ok;
}

// ------------- fused QKV GEMM: A(MxK) * Wqkvt(3072xK)^T + bias; split epilogue.
//   dbuf LDS + 1 barrier/K-step (stage overlaps MFMA), bank-swizzled fragments. -------------
__global__ __launch_bounds__(256) void gemm_qkv(const u16* __restrict__ A, const u16* __restrict__ Bt,
                                                const float* __restrict__ bias,
                                                u16* __restrict__ Qb, u16* __restrict__ KVb, int K) {
  __shared__ u16 As[2][128 * 32];
  __shared__ u16 Bs[2][128 * 32];
  int nbx = gridDim.x;
  int bid = blockIdx.y * nbx + blockIdx.x;
  int chunk = (nbx * gridDim.y) >> 3;
  int swz = (bid & 7) * chunk + (bid >> 3);
  int n0 = (swz % nbx) * 128, m0 = (swz / nbx) * 128;
  int t = threadIdx.x;
  int w = t >> 6, lane = t & 63, c = lane & 15, q = lane >> 4;
  int wm = w & 1, wn = w >> 1;
  int r0 = t >> 2;
  int kcs = ((t & 3) ^ ((t >> 3) & 3)) * 8;    // pre-swizzled source chunk
  const u16* Ag0 = A  + (size_t)(m0 + r0) * K + kcs;
  const u16* Ag1 = A  + (size_t)(m0 + 64 + r0) * K + kcs;
  const u16* Bg0 = Bt + (size_t)(n0 + r0) * K + kcs;
  const u16* Bg1 = Bt + (size_t)(n0 + 64 + r0) * K + kcs;
  int roff = (q ^ ((c >> 1) & 3)) * 8;         // swizzled read chunk
  f32x4 acc[4][4] = {};
  async16(Ag0, &As[0][t * 8]);
  async16(Ag1, &As[0][2048 + t * 8]);
  async16(Bg0, &Bs[0][t * 8]);
  async16(Bg1, &Bs[0][2048 + t * 8]);
  for (int k0 = 0; k0 < K; k0 += 32) {
    int cur = (k0 >> 5) & 1;
    __syncthreads();   // implicit vmcnt(0) drain: buf[cur] staged, buf[cur^1] free
    if (k0 + 32 < K) {
      async16(Ag0 + k0 + 32, &As[cur ^ 1][t * 8]);
      async16(Ag1 + k0 + 32, &As[cur ^ 1][2048 + t * 8]);
      async16(Bg0 + k0 + 32, &Bs[cur ^ 1][t * 8]);
      async16(Bg1 + k0 + 32, &Bs[cur ^ 1][2048 + t * 8]);
    }
    short8 af[4], bf[4];
    #pragma unroll
    for (int i = 0; i < 4; ++i) {
      af[i] = *(const short8*)&As[cur][(wm * 64 + i * 16 + c) * 32 + roff];
      bf[i] = *(const short8*)&Bs[cur][(wn * 64 + i * 16 + c) * 32 + roff];
    }
    #pragma unroll
    for (int i = 0; i < 4; ++i)
      #pragma unroll
      for (int j = 0; j < 4; ++j)
        acc[i][j] = __builtin_amdgcn_mfma_f32_16x16x32_bf16(af[i], bf[j], acc[i][j], 0, 0, 0);
  }
  int isq = (n0 < 2048);           // block-uniform
  #pragma unroll
  for (int i = 0; i < 4; ++i) {
    int mrow_base = m0 + wm * 64 + i * 16 + q * 4;
    #pragma unroll
    for (int j = 0; j < 4; ++j) {
      int coln = n0 + wn * 64 + j * 16 + c;
      float bv = bias[coln];
      #pragma unroll
      for (int r = 0; r < 4; ++r) {
        float v = acc[i][j][r] + bv;
        if (isq) Qb[(size_t)(mrow_base + r) * E_ + coln] = f2bf(v * QSCL);
        else     KVb[(size_t)(mrow_base + r) * KVLD_ + coln - 2048] = f2bf(v);
      }
    }
  }
}

// ------------- O-proj GEMM: C(MxN f32) = A(MxK) * Bt(NxK)^T + bias. -------------
__global__ __launch_bounds__(256) void gemm_k(const u16* __restrict__ A, const u16* __restrict__ Bt,
                                              const float* __restrict__ bias, float* __restrict__ Cout,
                                              int M, int N, int K) {
  __shared__ u16 As[2][128 * 32];
  __shared__ u16 Bs[2][128 * 32];
  int nbx = gridDim.x;
  int bid = blockIdx.y * nbx + blockIdx.x;
  int chunk = (nbx * gridDim.y) >> 3;
  int swz = (bid & 7) * chunk + (bid >> 3);
  int n0 = (swz % nbx) * 128, m0 = (swz / nbx) * 128;
  int t = threadIdx.x;
  int w = t >> 6, lane = t & 63, c = lane & 15, q = lane >> 4;
  int wm = w & 1, wn = w >> 1;
  int r0 = t >> 2;
  int kcs = ((t & 3) ^ ((t >> 3) & 3)) * 8;
  const u16* Ag0 = A  + (size_t)(m0 + r0) * K + kcs;
  const u16* Ag1 = A  + (size_t)(m0 + 64 + r0) * K + kcs;
  const u16* Bg0 = Bt + (size_t)(n0 + r0) * K + kcs;
  const u16* Bg1 = Bt + (size_t)(n0 + 64 + r0) * K + kcs;
  int roff = (q ^ ((c >> 1) & 3)) * 8;
  f32x4 acc[4][4] = {};
  async16(Ag0, &As[0][t * 8]);
  async16(Ag1, &As[0][2048 + t * 8]);
  async16(Bg0, &Bs[0][t * 8]);
  async16(Bg1, &Bs[0][2048 + t * 8]);
  for (int k0 = 0; k0 < K; k0 += 32) {
    int cur = (k0 >> 5) & 1;
    __syncthreads();
    if (k0 + 32 < K) {
      async16(Ag0 + k0 + 32, &As[cur ^ 1][t * 8]);
      async16(Ag1 + k0 + 32, &As[cur ^ 1][2048 + t * 8]);
      async16(Bg0 + k0 + 32, &Bs[cur ^ 1][t * 8]);
      async16(Bg1 + k0 + 32, &Bs[cur ^ 1][2048 + t * 8]);
    }
    short8 af[4], bf[4];
    #pragma unroll
    for (int i = 0; i < 4; ++i) {
      af[i] = *(const short8*)&As[cur][(wm * 64 + i * 16 + c) * 32 + roff];
      bf[i] = *(const short8*)&Bs[cur][(wn * 64 + i * 16 + c) * 32 + roff];
    }
    #pragma unroll
    for (int i = 0; i < 4; ++i)
      #pragma unroll
      for (int j = 0; j < 4; ++j)
        acc[i][j] = __builtin_amdgcn_mfma_f32_16x16x32_bf16(af[i], bf[j], acc[i][j], 0, 0, 0);
  }
  #pragma unroll
  for (int i = 0; i < 4; ++i) {
    int mrow_base = m0 + wm * 64 + i * 16 + q * 4;
    #pragma unroll
    for (int j = 0; j < 4; ++j) {
      int coln = n0 + wn * 64 + j * 16 + c;
      float bv = bias[coln];
      #pragma unroll
      for (int r = 0; r < 4; ++r)
        Cout[(size_t)(mrow_base + r) * N + coln] = acc[i][j][r] + bv;
    }
  }
}

// ------------- flash attention (R2-verified, 82us): 128 q-rows/block, 8 waves x 16 rows,
//               K/V dbuf in LDS, 1 barrier/tile, no-max softmax (bounded scores).
//               8 waves => 16 waves/CU (4/SIMD) at 80KB LDS. -------------
__global__ __launch_bounds__(512) void attn_k(const u16* __restrict__ Q, const u16* __restrict__ KVb,
                                              const u16* __restrict__ Vtg, const int* __restrict__ mask,
                                              const int* __restrict__ mflags, u16* __restrict__ O) {
  __shared__ u16 Ks[2][64 * 128]; // swizzled: phys chunk (row*16 + (kc ^ (row&15)))
  __shared__ u16 Vs[2][128 * 64]; // swizzled: phys chunk (n*8 + (kc ^ (n&7)))
  __shared__ u16 Ps[8 * 16 * 64]; // per-wave private (2KB each); permuted cols, swizzled
  int bid = blockIdx.x;
  int mt = bid & 15, h = (bid >> 4) & 15, bb = bid >> 8;
  int g = h & 3;                  // jnp.tile => head h uses group h % G
  int t = threadIdx.x, w = t >> 6, lane = t & 63, c = lane & 15, q = lane >> 4;
  int m0 = mt * 128;

  const u16* Qbase  = Q   + (size_t)(bb * S_ + m0) * E_ + h * HD_;
  const u16* Kbase  = KVb + (size_t)bb * S_ * KVLD_ + g * HD_;
  const u16* Vtbase = Vtg + (size_t)(bb * G_ + g) * HD_ * S_;

  // staging addresses (512 threads: 32 K-rows / 64 V-rows per async round)
  int krow0 = t >> 4;                         // 0..31
  int kkc   = ((t & 15) ^ (krow0 & 15)) * 8;
  const u16* Kst = Kbase + (size_t)krow0 * KVLD_ + kkc;
  int vn0 = t >> 3;                           // 0..63
  int vkc = ((t & 7) ^ (vn0 & 7)) * 8;
  const u16* Vst = Vtbase + (size_t)vn0 * S_ + vkc;

  // P LDS addresses: write 4 rows (b64 each), read 2 chunks (b128)
  int pwa[4], pra[2];
  #pragma unroll
  for (int r = 0; r < 4; ++r) {
    int row = q * 4 + r;
    pwa[r] = w * 1024 + row * 64 + (((c >> 1) ^ (row & 7)) * 8) + (c & 1) * 4;
  }
  #pragma unroll
  for (int ks = 0; ks < 2; ++ks)
    pra[ks] = w * 1024 + c * 64 + (((ks * 4 + q) ^ (c & 7)) * 8);

  // Q fragments in registers (pre-scaled by QSCL); wave w owns rows [w*16, w*16+16)
  short8 aq[4];
  #pragma unroll
  for (int k0 = 0; k0 < 4; ++k0)
    aq[k0] = *(const short8*)&Qbase[(size_t)(w * 16 + c) * E_ + k0 * 32 + q * 8];

  const short8 ones = {(short)0x3F80, (short)0x3F80, (short)0x3F80, (short)0x3F80,
                       (short)0x3F80, (short)0x3F80, (short)0x3F80, (short)0x3F80};

  f32x4 Oa[8] = {};
  f32x4 lacc = {};

  // prefetch tile 0 into buffer 0
  #pragma unroll
  for (int p = 0; p < 2; ++p)
    async16(Kst + (size_t)(p * 32) * KVLD_, &Ks[0][p * 4096 + t * 8]);
  #pragma unroll
  for (int p = 0; p < 2; ++p)
    async16(Vst + (size_t)(p * 64) * S_, &Vs[0][p * 4096 + t * 8]);

  for (int kv0 = 0; kv0 < S_; kv0 += 64) {
    int cur = (kv0 >> 6) & 1;
    // single barrier per tile: drain guarantees buf[cur] staged and buf[cur^1] free
    __syncthreads();
    if (kv0 + 64 < S_) {           // prefetch next tile into the other buffer
      #pragma unroll
      for (int p = 0; p < 2; ++p)
        async16(Kst + (size_t)(kv0 + 64 + p * 32) * KVLD_, &Ks[cur ^ 1][p * 4096 + t * 8]);
      #pragma unroll
      for (int p = 0; p < 2; ++p)
        async16(Vst + (size_t)(p * 64) * S_ + kv0 + 64, &Vs[cur ^ 1][p * 4096 + t * 8]);
    }
    const u16* K_ = Ks[cur];
    const u16* V_ = Vs[cur];

    // QK^T (log2 domain)
    f32x4 sc[4] = {};
    #pragma unroll
    for (int k0 = 0; k0 < 4; ++k0) {
      short8 bk[4];
      #pragma unroll
      for (int ns = 0; ns < 4; ++ns)
        bk[ns] = *(const short8*)&K_[(ns * 16 + c) * 128 + (((k0 * 4 + q) ^ c) * 8)];
      #pragma unroll
      for (int ns = 0; ns < 4; ++ns)
        sc[ns] = __builtin_amdgcn_mfma_f32_16x16x32_bf16(aq[k0], bk[ns], sc[ns], 0, 0, 0);
    }
    // rare mask path
    {
      int flag = mflags[bb * 4096 + (mt * 8 + w) * 32 + (kv0 >> 6)];
      if (!flag) {
        #pragma unroll
        for (int r = 0; r < 4; ++r) {
          int qrow = m0 + w * 16 + q * 4 + r;
          const int* mrow = mask + ((size_t)bb * S_ + qrow) * S_ + kv0;
          #pragma unroll
          for (int ns = 0; ns < 4; ++ns)
            if (mrow[ns * 16 + c] == 0) sc[ns][r] = MASKED_L2;
        }
      }
    }
    // p = exp2(sc); pack bf16 (round-half-up), 4 permuted cols/row
    #pragma unroll
    for (int r = 0; r < 4; ++r) {
      u32 u[4];
      #pragma unroll
      for (int ns = 0; ns < 4; ++ns) {
        float p = __builtin_amdgcn_exp2f(sc[ns][r]);
        u[ns] = __float_as_uint(p) + 0x8000u;
      }
      uint2 pk;
      pk.x = __builtin_amdgcn_perm(u[1], u[0], 0x07060302);
      pk.y = __builtin_amdgcn_perm(u[3], u[2], 0x07060302);
      *(uint2*)&Ps[pwa[r]] = pk;
    }
    __asm__ volatile("" ::: "memory");   // Ps is wave-private: LDS pipe is in-order per wave
    // PV + row-sums
    #pragma unroll
    for (int ks = 0; ks < 2; ++ks) {
      short8 ap = *(const short8*)&Ps[pra[ks]];
      lacc = __builtin_amdgcn_mfma_f32_16x16x32_bf16(ap, ones, lacc, 0, 0, 0);
      #pragma unroll
      for (int d = 0; d < 8; ++d) {
        short8 bv = *(const short8*)&V_[(d * 16 + c) * 64 + (((ks * 4 + q) ^ (c & 7)) * 8)];
        Oa[d] = __builtin_amdgcn_mfma_f32_16x16x32_bf16(ap, bv, Oa[d], 0, 0, 0);
      }
    }
  }
  {
    float inv[4];
    #pragma unroll
    for (int r = 0; r < 4; ++r) inv[r] = 1.0f / lacc[r];
    #pragma unroll
    for (int d = 0; d < 8; ++d)
      #pragma unroll
      for (int r = 0; r < 4; ++r) {
        size_t off = (size_t)(bb * S_ + m0 + w * 16 + q * 4 + r) * E_ + h * HD_ + d * 16 + c;
        O[off] = f2bf(Oa[d][r] * inv[r]);
      }
  }
}

extern "C" void kernel_launch(void* const* d_in, const int* in_sizes, int n_in,
                              void* d_out, int out_size, void* d_ws, size_t ws_size,
                              hipStream_t stream) {
  const float* x    = (const float*)d_in[0];
  const int*   mask = (const int*)d_in[1];
  const float* Wq   = (const float*)d_in[2];
  const float* bq   = (const float*)d_in[3];
  const float* Wk   = (const float*)d_in[4];
  const float* bk   = (const float*)d_in[5];
  const float* Wv   = (const float*)d_in[6];
  const float* bv   = (const float*)d_in[7];
  const float* Wo   = (const float*)d_in[8];
  const float* bo   = (const float*)d_in[9];
  float* out = (float*)d_out;

  char* ws = (char*)d_ws;
  u16* xb    = (u16*)ws; ws += (size_t)M_ * E_ * 2;
  u16* Wqkvt = (u16*)ws; ws += (size_t)QKVN_ * E_ * 2;
  u16* Wot   = (u16*)ws; ws += (size_t)E_ * E_ * 2;
  u16* Qb    = (u16*)ws; ws += (size_t)M_ * E_ * 2;
  u16* KVb   = (u16*)ws; ws += (size_t)M_ * KVLD_ * 2;
  u16* Ob    = (u16*)ws; ws += (size_t)M_ * E_ * 2;
  u16* Vtg   = (u16*)ws; ws += (size_t)B_ * G_ * HD_ * S_ * 2;
  int* mfl   = (int*)ws; ws += (size_t)B_ * 128 * 32 * 4;
  float* bqkv = (float*)ws; ws += QKVN_ * 4;

  int n4 = M_ * E_ / 4;
  cast_plus<<<(n4 + 255) / 256 + 12, 256, 0, stream>>>(x, xb, n4, bq, bk, bv, bqkv);
  transpose_cast4<<<2560, 256, 0, stream>>>(Wq, Wk, Wv, Wo, Wqkvt, Wot);
  mask_flags<<<B_ * 128 * 32 / 4, 256, 0, stream>>>(mask, mfl);

  gemm_qkv<<<dim3(QKVN_ / 128, M_ / 128), 256, 0, stream>>>(xb, Wqkvt, bqkv, Qb, KVb, E_);
  transpose_v<<<dim3(M_ / 64, GD_ / 64), 256, 0, stream>>>(KVb, Vtg);

  attn_k<<<B_ * H_ * (S_ / 128), 512, 0, stream>>>(Qb, KVb, Vtg, mask, mfl, Ob);

  gemm_k<<<dim3(E_ / 128, M_ / 128), 256, 0, stream>>>(Ob, Wot, bo, out, M_, E_, E_);
}